// Round 6
// baseline (243.787 us; speedup 1.0000x reference)
//
#include <hip/hip_runtime.h>
#include <hip/hip_bf16.h>
#include <stdint.h>

typedef short bf16x8 __attribute__((ext_vector_type(8)));
typedef float f32x4  __attribute__((ext_vector_type(4)));
typedef float f32x16 __attribute__((ext_vector_type(16)));
typedef unsigned short u16;
typedef unsigned int   u32;

#define BATCH 4
#define PTOT  4096   // H*W
#define CINT  128    // inter channels
// (1/sqrt(128)) * log2(e): fold QK scale + exp2 base change into theta
#define QK_SCALE 0.12751744f

__device__ __forceinline__ u32 pk_bf16(float a, float b) {
  u32 r;
  asm("v_cvt_pk_bf16_f32 %0, %1, %2" : "=v"(r) : "v"(a), "v"(b));
  return r;
}
__device__ __forceinline__ u16 f2bf(float x) { return (u16)pk_bf16(x, x); }
__device__ __forceinline__ float bf2f(u16 v) { return __uint_as_float(((u32)v) << 16); }
__device__ __forceinline__ float max3f(float a, float b, float c) {
  return fmaxf(fmaxf(a, b), c);
}

__device__ __forceinline__ f32x4 mfma16(bf16x8 a, bf16x8 b, f32x4 c) {
  return __builtin_amdgcn_mfma_f32_16x16x32_bf16(a, b, c, 0, 0, 0);
}
__device__ __forceinline__ f32x16 mfma32(bf16x8 a, bf16x8 b, f32x16 c) {
  return __builtin_amdgcn_mfma_f32_32x32x16_bf16(a, b, c, 0, 0, 0);
}
__device__ __forceinline__ void gload16(const u16* g, u16* l) {
  __builtin_amdgcn_global_load_lds((const __attribute__((address_space(1))) u32*)g,
                                   (__attribute__((address_space(3))) u32*)l, 16, 0, 0);
}
// 32x32 MFMA A-operand fragment of P from 8 softmax values (verified in R4)
__device__ __forceinline__ bf16x8 mkfrag(float a0, float a1, float a2, float a3,
                                         float a4, float a5, float a6, float a7) {
  u32 A = pk_bf16(a0, a1), B = pk_bf16(a2, a3);
  u32 C = pk_bf16(a4, a5), D = pk_bf16(a6, a7);
  asm volatile("v_permlane32_swap_b32 %0, %1" : "+v"(A), "+v"(C));
  asm volatile("v_permlane32_swap_b32 %0, %1" : "+v"(B), "+v"(D));
  union { u32 w[4]; bf16x8 v; } u;
  u.w[0] = A; u.w[1] = B; u.w[2] = C; u.w[3] = D;
  return u.v;
}

// ---------------- fused projections: z==0 theta(query), z==1 phi+g(reference) ----------------
__global__ void k_proj_all(const float* __restrict__ Xq, const float* __restrict__ Xr,
                           const float* __restrict__ Wt, const float* __restrict__ bt,
                           const float* __restrict__ Wp, const float* __restrict__ bp,
                           const float* __restrict__ Wg, const float* __restrict__ bg,
                           u16* __restrict__ TH, u16* __restrict__ PH, u16* __restrict__ Gm) {
  const int b = blockIdx.y, p0 = blockIdx.x * 64;
  const int t = threadIdx.x, lane = t & 63, w = t >> 6;
  const int m_ = lane & 15, h = lane >> 4;
  __shared__ __align__(16) u16 Bt[64][40];
  __shared__ __align__(16) u16 W1[128][40];
  __shared__ __align__(16) u16 W2[128][40];
  const int p = t & 63, cg = t >> 6;
  const int wrow = t >> 1, whalf = t & 1;
  if (blockIdx.z == 0) {
    const int Cin = 256;
    const float* xb = Xq + (size_t)b * Cin * PTOT;
    f32x4 acc[4][2];
#pragma unroll
    for (int i = 0; i < 4; i++) { acc[i][0] = (f32x4)0.0f; acc[i][1] = (f32x4)0.0f; }
    for (int k0 = 0; k0 < Cin; k0 += 32) {
      __syncthreads();
      { // x^T tile fp32 -> bf16
        const float* sx = xb + (size_t)(k0 + 8 * cg) * PTOT + p0 + p;
        float v0 = sx[0],        v1 = sx[PTOT],   v2 = sx[2*PTOT], v3 = sx[3*PTOT];
        float v4 = sx[4*PTOT],   v5 = sx[5*PTOT], v6 = sx[6*PTOT], v7 = sx[7*PTOT];
        *(uint2*)&Bt[p][8*cg]     = make_uint2(pk_bf16(v0,v1), pk_bf16(v2,v3));
        *(uint2*)&Bt[p][8*cg + 4] = make_uint2(pk_bf16(v4,v5), pk_bf16(v6,v7));
      }
      { // Wt fp32 -> bf16 stage
        const float* sw = Wt + (size_t)wrow * Cin + k0 + whalf * 16;
        float4 w0 = *(const float4*)sw,     w1 = *(const float4*)(sw + 4);
        float4 w2 = *(const float4*)(sw+8), w3 = *(const float4*)(sw + 12);
        *(uint4*)&W1[wrow][whalf*16]   = make_uint4(pk_bf16(w0.x,w0.y), pk_bf16(w0.z,w0.w),
                                                    pk_bf16(w1.x,w1.y), pk_bf16(w1.z,w1.w));
        *(uint4*)&W1[wrow][whalf*16+8] = make_uint4(pk_bf16(w2.x,w2.y), pk_bf16(w2.z,w2.w),
                                                    pk_bf16(w3.x,w3.y), pk_bf16(w3.z,w3.w));
      }
      __syncthreads();
      bf16x8 bf0 = *(const bf16x8*)&W1[w*32 + m_][8*h];
      bf16x8 bf1 = *(const bf16x8*)&W1[w*32 + 16 + m_][8*h];
#pragma unroll
      for (int mb = 0; mb < 4; mb++) {
        bf16x8 af = *(const bf16x8*)&Bt[mb*16 + m_][8*h];
        acc[mb][0] = mfma16(af, bf0, acc[mb][0]);
        acc[mb][1] = mfma16(af, bf1, acc[mb][1]);
      }
    }
    u16* ob = TH + (size_t)b * PTOT * CINT;
#pragma unroll
    for (int mb = 0; mb < 4; mb++)
#pragma unroll
      for (int nb = 0; nb < 2; nb++) {
        int c = w*32 + nb*16 + m_;
        float bv = bt[c];
#pragma unroll
        for (int r = 0; r < 4; r++) {
          int pp = p0 + mb*16 + 4*h + r;
          ob[(size_t)pp * CINT + c] = f2bf((acc[mb][nb][r] + bv) * QK_SCALE);
        }
      }
  } else {
    const int Cin = 512;
    const float* xb = Xr + (size_t)b * Cin * PTOT;
    f32x4 accp[4][2];
    f32x4 accg[2][4];
#pragma unroll
    for (int i = 0; i < 4; i++) { accp[i][0] = (f32x4)0.0f; accp[i][1] = (f32x4)0.0f; }
#pragma unroll
    for (int i = 0; i < 2; i++)
#pragma unroll
      for (int j = 0; j < 4; j++) accg[i][j] = (f32x4)0.0f;
    for (int k0 = 0; k0 < Cin; k0 += 32) {
      __syncthreads();
      {
        const float* sx = xb + (size_t)(k0 + 8 * cg) * PTOT + p0 + p;
        float v0 = sx[0],        v1 = sx[PTOT],   v2 = sx[2*PTOT], v3 = sx[3*PTOT];
        float v4 = sx[4*PTOT],   v5 = sx[5*PTOT], v6 = sx[6*PTOT], v7 = sx[7*PTOT];
        *(uint2*)&Bt[p][8*cg]     = make_uint2(pk_bf16(v0,v1), pk_bf16(v2,v3));
        *(uint2*)&Bt[p][8*cg + 4] = make_uint2(pk_bf16(v4,v5), pk_bf16(v6,v7));
      }
      {
        const float* sw = Wp + (size_t)wrow * Cin + k0 + whalf * 16;
        float4 w0 = *(const float4*)sw,     w1 = *(const float4*)(sw + 4);
        float4 w2 = *(const float4*)(sw+8), w3 = *(const float4*)(sw + 12);
        *(uint4*)&W1[wrow][whalf*16]   = make_uint4(pk_bf16(w0.x,w0.y), pk_bf16(w0.z,w0.w),
                                                    pk_bf16(w1.x,w1.y), pk_bf16(w1.z,w1.w));
        *(uint4*)&W1[wrow][whalf*16+8] = make_uint4(pk_bf16(w2.x,w2.y), pk_bf16(w2.z,w2.w),
                                                    pk_bf16(w3.x,w3.y), pk_bf16(w3.z,w3.w));
        const float* sg = Wg + (size_t)wrow * Cin + k0 + whalf * 16;
        float4 g0 = *(const float4*)sg,     g1 = *(const float4*)(sg + 4);
        float4 g2 = *(const float4*)(sg+8), g3 = *(const float4*)(sg + 12);
        *(uint4*)&W2[wrow][whalf*16]   = make_uint4(pk_bf16(g0.x,g0.y), pk_bf16(g0.z,g0.w),
                                                    pk_bf16(g1.x,g1.y), pk_bf16(g1.z,g1.w));
        *(uint4*)&W2[wrow][whalf*16+8] = make_uint4(pk_bf16(g2.x,g2.y), pk_bf16(g2.z,g2.w),
                                                    pk_bf16(g3.x,g3.y), pk_bf16(g3.z,g3.w));
      }
      __syncthreads();
      {
        bf16x8 bf0 = *(const bf16x8*)&W1[w*32 + m_][8*h];
        bf16x8 bf1 = *(const bf16x8*)&W1[w*32 + 16 + m_][8*h];
#pragma unroll
        for (int mb = 0; mb < 4; mb++) {
          bf16x8 af = *(const bf16x8*)&Bt[mb*16 + m_][8*h];
          accp[mb][0] = mfma16(af, bf0, accp[mb][0]);
          accp[mb][1] = mfma16(af, bf1, accp[mb][1]);
        }
      }
      {
        bf16x8 bfr[4];
#pragma unroll
        for (int nb = 0; nb < 4; nb++) bfr[nb] = *(const bf16x8*)&Bt[nb*16 + m_][8*h];
#pragma unroll
        for (int mb = 0; mb < 2; mb++) {
          bf16x8 af = *(const bf16x8*)&W2[w*32 + mb*16 + m_][8*h];
#pragma unroll
          for (int nb = 0; nb < 4; nb++) accg[mb][nb] = mfma16(af, bfr[nb], accg[mb][nb]);
        }
      }
    }
    {
      u16* ob = PH + (size_t)b * PTOT * CINT;
#pragma unroll
      for (int mb = 0; mb < 4; mb++)
#pragma unroll
        for (int nb = 0; nb < 2; nb++) {
          int c = w*32 + nb*16 + m_;
          float bv = bp[c];
#pragma unroll
          for (int r = 0; r < 4; r++) {
            int pp = p0 + mb*16 + 4*h + r;
            ob[(size_t)pp * CINT + c] = f2bf(accp[mb][nb][r] + bv);
          }
        }
    }
    {
      u16* ob = Gm + (size_t)b * CINT * PTOT;
#pragma unroll
      for (int mb = 0; mb < 2; mb++)
#pragma unroll
        for (int nb = 0; nb < 4; nb++) {
          int pidx = p0 + nb*16 + m_;
#pragma unroll
          for (int r = 0; r < 4; r++) {
            int c = w*32 + mb*16 + 4*h + r;
            ob[(size_t)c * PTOT + pidx] = f2bf(accg[mb][nb][r] + bg[c]);
          }
        }
    }
  }
}

// ---------------- flash attention: 32x32 MFMA, K dbuf + V single (48.5 KiB -> 3 blocks/CU) ----
// l-sum via MFMA ones-trick; max via max3 tree + permlane32_swap; counted vmcnt pipeline.
template<int SPLIT>
__global__ __launch_bounds__(256, 3)
void k_attn(const u16* __restrict__ TH, const u16* __restrict__ PH,
            const u16* __restrict__ G, u16* __restrict__ U,
            float* __restrict__ ML, u16* __restrict__ Y) {
  constexpr int LSPLIT = (SPLIT == 4) ? 2 : ((SPLIT == 2) ? 1 : 0);
  constexpr int NITER = 64 >> LSPLIT;
  const int total = 32 * BATCH * SPLIT;
  const int did = blockIdx.x;
  const int gid = (did & 7) * (total >> 3) + (did >> 3);   // XCD-contiguous
  const int qb = gid & 31, grp = gid >> 5;
  const int z = grp & (SPLIT - 1), b = grp >> LSPLIT;
  const int t = threadIdx.x, lane = t & 63, w = t >> 6;
  const int l31 = lane & 31, hi = lane >> 5;
  __shared__ __align__(16) u16 Kl[2][64 * 128];
  __shared__ __align__(16) u16 Vl[128 * 64];
  __shared__ float Ls[4][32];
  const u16* thb = TH + (size_t)b * PTOT * CINT;
  const u16* phb = PH + (size_t)b * PTOT * CINT;
  const u16* gb  = G  + (size_t)b * CINT * PTOT;
  const int qw = qb * 128 + w * 32;
  bf16x8 qf[8];
  {
    const u16* qr = thb + (size_t)(qw + l31) * CINT + hi * 8;
#pragma unroll
    for (int cs = 0; cs < 8; cs++) qf[cs] = *(const bf16x8*)(qr + cs * 16);
  }
  bf16x8 ones;
  {
    union { u32 w[4]; bf16x8 v; } u;
    u.w[0] = u.w[1] = u.w[2] = u.w[3] = 0x3F803F80u;
    ones = u.v;
  }
  f32x16 yacc[4];
#pragma unroll
  for (int i = 0; i < 4; i++) yacc[i] = (f32x16)0.0f;
  f32x16 lacc = (f32x16)0.0f;
  float mrun = -3.0e38f;
  const int it0 = z * NITER;

  auto STAGE_K = [&](int bb, int it) {
    const int k0 = it * 64;
#pragma unroll
    for (int i = 0; i < 4; i++) {
      const int s = w * 4 + i;                   // 16 segments x 512 u16
      const int row = s * 4 + (lane >> 4);
      const int cl = ((lane & 15) * 8) ^ ((row & 15) << 3);  // inverse swizzle (16 slots)
      gload16(phb + (size_t)(k0 + row) * CINT + cl, &Kl[bb][s * 512]);
    }
  };
  auto STAGE_V = [&](int it) {
    const int k0 = it * 64;
#pragma unroll
    for (int i = 0; i < 4; i++) {
      const int s = w * 4 + i;
      const int row = s * 8 + (lane >> 3);
      const int cl = ((lane & 7) * 8) ^ ((row & 7) << 3);
      gload16(gb + (size_t)row * PTOT + k0 + cl, &Vl[s * 512]);
    }
  };

  STAGE_K(0, it0);
  int cur = 0;
  for (int it = it0; it < it0 + NITER; ++it) {
    asm volatile("s_waitcnt vmcnt(0)" ::: "memory");  // K[it] landed
    __builtin_amdgcn_s_barrier();
    __builtin_amdgcn_sched_barrier(0);
    STAGE_V(it);                                       // 4 loads (oldest)
    const int itn = (it + 1 < it0 + NITER) ? it + 1 : it;
    STAGE_K(cur ^ 1, itn);                             // 4 more in flight
    // ---- QK: S^T[k][q] ----
    f32x16 sa0 = (f32x16)0.0f, sa1 = (f32x16)0.0f;
    __builtin_amdgcn_s_setprio(1);
#pragma unroll
    for (int cs = 0; cs < 8; cs++) {
      const int xc = cs * 16 + hi * 8;
      const int r0 = l31, r1 = 32 + l31;
      bf16x8 a0 = *(const bf16x8*)&Kl[cur][r0 * 128 + (xc ^ ((r0 & 15) << 3))];
      bf16x8 a1 = *(const bf16x8*)&Kl[cur][r1 * 128 + (xc ^ ((r1 & 15) << 3))];
      sa0 = mfma32(a0, qf[cs], sa0);
      sa1 = mfma32(a1, qf[cs], sa1);
    }
    __builtin_amdgcn_s_setprio(0);
    // ---- max via max3 tree ----
    float t0 = max3f(sa0[0],  sa0[1],  sa0[2]);
    float t1 = max3f(sa0[3],  sa0[4],  sa0[5]);
    float t2 = max3f(sa0[6],  sa0[7],  sa0[8]);
    float t3 = max3f(sa0[9],  sa0[10], sa0[11]);
    float t4 = max3f(sa0[12], sa0[13], sa0[14]);
    float t5 = max3f(sa1[0],  sa1[1],  sa1[2]);
    float t6 = max3f(sa1[3],  sa1[4],  sa1[5]);
    float t7 = max3f(sa1[6],  sa1[7],  sa1[8]);
    float t8 = max3f(sa1[9],  sa1[10], sa1[11]);
    float t9 = max3f(sa1[12], sa1[13], sa1[14]);
    float ta = fmaxf(sa0[15], sa1[15]);
    float u0 = max3f(t0, t1, t2);
    float u1 = max3f(t3, t4, t5);
    float u2 = max3f(t6, t7, t8);
    float u3 = max3f(t9, ta, u0);
    float tm = max3f(u1, u2, u3);
    {  // cross-half max via permlane32_swap (no LDS path)
      u32 xa = __float_as_uint(tm), xb = xa;
      asm volatile("v_permlane32_swap_b32 %0, %1" : "+v"(xa), "+v"(xb));
      tm = fmaxf(tm, fmaxf(__uint_as_float(xa), __uint_as_float(xb)));
    }
    if (!__all(tm <= mrun + 8.0f)) {                  // defer-max (T13)
      float mnew = fmaxf(mrun, tm);
      float f = exp2f(mrun - mnew);
      mrun = mnew;
      lacc *= f;
#pragma unroll
      for (int i = 0; i < 4; i++) yacc[i] *= f;
    }
    // ---- P fragments + l via MFMA ones-trick ----
    bf16x8 pa[4];
    pa[0] = mkfrag(exp2f(sa0[0] - mrun),  exp2f(sa0[1] - mrun),  exp2f(sa0[2] - mrun),
                   exp2f(sa0[3] - mrun),  exp2f(sa0[4] - mrun),  exp2f(sa0[5] - mrun),
                   exp2f(sa0[6] - mrun),  exp2f(sa0[7] - mrun));
    pa[1] = mkfrag(exp2f(sa0[8] - mrun),  exp2f(sa0[9] - mrun),  exp2f(sa0[10] - mrun),
                   exp2f(sa0[11] - mrun), exp2f(sa0[12] - mrun), exp2f(sa0[13] - mrun),
                   exp2f(sa0[14] - mrun), exp2f(sa0[15] - mrun));
    pa[2] = mkfrag(exp2f(sa1[0] - mrun),  exp2f(sa1[1] - mrun),  exp2f(sa1[2] - mrun),
                   exp2f(sa1[3] - mrun),  exp2f(sa1[4] - mrun),  exp2f(sa1[5] - mrun),
                   exp2f(sa1[6] - mrun),  exp2f(sa1[7] - mrun));
    pa[3] = mkfrag(exp2f(sa1[8] - mrun),  exp2f(sa1[9] - mrun),  exp2f(sa1[10] - mrun),
                   exp2f(sa1[11] - mrun), exp2f(sa1[12] - mrun), exp2f(sa1[13] - mrun),
                   exp2f(sa1[14] - mrun), exp2f(sa1[15] - mrun));
    __builtin_amdgcn_s_setprio(1);
    lacc = mfma32(pa[0], ones, lacc);
    lacc = mfma32(pa[1], ones, lacc);
    lacc = mfma32(pa[2], ones, lacc);
    lacc = mfma32(pa[3], ones, lacc);
    __builtin_amdgcn_s_setprio(0);
    asm volatile("s_waitcnt vmcnt(4)" ::: "memory");  // V[it] landed (K[it+1] in flight)
    __builtin_amdgcn_s_barrier();
    __builtin_amdgcn_sched_barrier(0);
    // ---- PV: y[q][c'] += P[q][k] * V[k][c'] ----
    __builtin_amdgcn_s_setprio(1);
#pragma unroll
    for (int fs = 0; fs < 4; fs++) {
      const int xk = fs * 16 + hi * 8;
#pragma unroll
      for (int nt = 0; nt < 4; nt++) {
        const int r = nt * 32 + l31;
        bf16x8 vf = *(const bf16x8*)&Vl[r * 64 + (xk ^ ((r & 7) << 3))];
        yacc[nt] = mfma32(pa[fs], vf, yacc[nt]);
      }
    }
    __builtin_amdgcn_s_setprio(0);
    cur ^= 1;
  }
  // ---- epilogue ----
  if constexpr (SPLIT > 1) {
    u16* ub = U + (size_t)(z * BATCH + b) * PTOT * CINT;
#pragma unroll
    for (int reg = 0; reg < 16; reg++) {
      const int qq = qw + (reg & 3) + 8 * (reg >> 2) + 4 * hi;
      u16* row = ub + (size_t)qq * CINT + l31;
      row[0]  = f2bf(yacc[0][reg]);
      row[32] = f2bf(yacc[1][reg]);
      row[64] = f2bf(yacc[2][reg]);
      row[96] = f2bf(yacc[3][reg]);
    }
    float* mlb = ML + (size_t)(z * BATCH + b) * PTOT * 2;
    if (l31 == 0) {   // lanes 0 and 32 hold l for 16 rows each
#pragma unroll
      for (int reg = 0; reg < 16; reg++) {
        const int row = (reg & 3) + 8 * (reg >> 2) + 4 * hi;
        mlb[(size_t)(qw + row) * 2 + 1] = lacc[reg];
      }
    }
    if (lane < 32) mlb[(size_t)(qw + lane) * 2] = mrun;
  } else {
    if (l31 == 0) {
#pragma unroll
      for (int reg = 0; reg < 16; reg++)
        Ls[w][(reg & 3) + 8 * (reg >> 2) + 4 * hi] = lacc[reg];
    }
    asm volatile("s_waitcnt lgkmcnt(0)" ::: "memory");
    __builtin_amdgcn_sched_barrier(0);
    const float inv = 1.0f / Ls[w][l31];
    u16* yb = Y + (size_t)b * PTOT * CINT;
#pragma unroll
    for (int reg = 0; reg < 16; reg++) {
      const int qq = qw + (reg & 3) + 8 * (reg >> 2) + 4 * hi;
      u16* row = yb + (size_t)qq * CINT + l31;
      row[0]  = f2bf(yacc[0][reg] * inv);
      row[32] = f2bf(yacc[1][reg] * inv);
      row[64] = f2bf(yacc[2][reg] * inv);
      row[96] = f2bf(yacc[3][reg] * inv);
    }
  }
}

// ---------------- output projection + residual, with fused SPLIT-combine ----------------
template<int SPLIT>
__global__ void k_outproj(const float* __restrict__ Q, const float* __restrict__ Wo,
                          const float* __restrict__ bo, const u16* __restrict__ UY,
                          const float* __restrict__ ML, float* __restrict__ O) {
  const int p0 = blockIdx.x * 64, chh = blockIdx.y, b = blockIdx.z;
  const int t = threadIdx.x, lane = t & 63, w = t >> 6;
  const int m_ = lane & 15, h = lane >> 4;
  __shared__ __align__(16) u16 Wl[128][136];
  __shared__ __align__(16) u16 Yl[64][136];
  {  // Wo fp32 -> bf16 stage
    int row = t >> 1, cc = t & 1;
    const float* src = Wo + (size_t)(chh*128 + row) * CINT + cc*64;
#pragma unroll
    for (int i = 0; i < 8; i++) {
      float4 a = *(const float4*)(src + i*8), c = *(const float4*)(src + i*8 + 4);
      *(uint4*)&Wl[row][cc*64 + i*8] = make_uint4(pk_bf16(a.x,a.y), pk_bf16(a.z,a.w),
                                                  pk_bf16(c.x,c.y), pk_bf16(c.z,c.w));
    }
  }
  {  // Y stage: combine SPLIT partials (or direct copy)
    int row = t >> 2, cc = t & 3;
    int p = p0 + row;
    if constexpr (SPLIT > 1) {
      float msv[SPLIT], lsv[SPLIT];
      float M = -3.0e38f;
#pragma unroll
      for (int s = 0; s < SPLIT; s++) {
        const float* mp = ML + ((size_t)(s * BATCH + b) * PTOT + p) * 2;
        msv[s] = mp[0]; lsv[s] = mp[1];
        M = fmaxf(M, msv[s]);
      }
      float L = 0.0f;
#pragma unroll
      for (int s = 0; s < SPLIT; s++) { msv[s] = exp2f(msv[s] - M); L += lsv[s] * msv[s]; }
      float inv = 1.0f / L;
#pragma unroll
      for (int s = 0; s < SPLIT; s++) msv[s] *= inv;
#pragma unroll
      for (int i = 0; i < 4; i++) {
        float a0 = 0, a1 = 0, a2 = 0, a3 = 0, a4 = 0, a5 = 0, a6 = 0, a7 = 0;
#pragma unroll
        for (int s = 0; s < SPLIT; s++) {
          uint4 v = *(const uint4*)(UY + ((size_t)(s * BATCH + b) * PTOT + p) * CINT + cc*32 + i*8);
          float f = msv[s];
          a0 += bf2f((u16)(v.x & 0xffff)) * f;  a1 += bf2f((u16)(v.x >> 16)) * f;
          a2 += bf2f((u16)(v.y & 0xffff)) * f;  a3 += bf2f((u16)(v.y >> 16)) * f;
          a4 += bf2f((u16)(v.z & 0xffff)) * f;  a5 += bf2f((u16)(v.z >> 16)) * f;
          a6 += bf2f((u16)(v.w & 0xffff)) * f;  a7 += bf2f((u16)(v.w >> 16)) * f;
        }
        *(uint4*)&Yl[row][cc*32 + i*8] = make_uint4(pk_bf16(a0,a1), pk_bf16(a2,a3),
                                                    pk_bf16(a4,a5), pk_bf16(a6,a7));
      }
    } else {
      const u16* src = UY + ((size_t)b * PTOT + p) * CINT + cc*32;
#pragma unroll
      for (int i = 0; i < 4; i++)
        *(uint4*)&Yl[row][cc*32 + i*8] = *(const uint4*)(src + i*8);
    }
  }
  __syncthreads();
  f32x4 acc[2][4];
#pragma unroll
  for (int i = 0; i < 2; i++)
#pragma unroll
    for (int j = 0; j < 4; j++) acc[i][j] = (f32x4)0.0f;
#pragma unroll
  for (int ks = 0; ks < 4; ks++) {
    bf16x8 bfr[4];
#pragma unroll
    for (int nb = 0; nb < 4; nb++) bfr[nb] = *(const bf16x8*)&Yl[nb*16 + m_][ks*32 + 8*h];
#pragma unroll
    for (int mb = 0; mb < 2; mb++) {
      bf16x8 af = *(const bf16x8*)&Wl[w*32 + mb*16 + m_][ks*32 + 8*h];
#pragma unroll
      for (int nb = 0; nb < 4; nb++) acc[mb][nb] = mfma16(af, bfr[nb], acc[mb][nb]);
    }
  }
  const size_t cob = (size_t)b * 256 + (size_t)chh * 128;
#pragma unroll
  for (int mb = 0; mb < 2; mb++)
#pragma unroll
    for (int nb = 0; nb < 4; nb++) {
      int pidx = p0 + nb*16 + m_;
#pragma unroll
      for (int r = 0; r < 4; r++) {
        int co = w*32 + mb*16 + 4*h + r;
        size_t idx = (cob + co) * PTOT + pidx;
        O[idx] = Q[idx] + acc[mb][nb][r] + bo[chh*128 + co];
      }
    }
}

extern "C" void kernel_launch(void* const* d_in, const int* in_sizes, int n_in,
                              void* d_out, int out_size, void* d_ws, size_t ws_size,
                              hipStream_t stream) {
  const float* q_in = (const float*)d_in[0];
  const float* ref  = (const float*)d_in[1];
  const float* Wg   = (const float*)d_in[2];
  const float* bg   = (const float*)d_in[3];
  const float* Wt   = (const float*)d_in[4];
  const float* bt   = (const float*)d_in[5];
  const float* Wp   = (const float*)d_in[6];
  const float* bp   = (const float*)d_in[7];
  const float* Wo   = (const float*)d_in[8];
  const float* bo   = (const float*)d_in[9];
  float* out = (float*)d_out;
  char* ws = (char*)d_ws;

  u16* TH = (u16*)(ws + 0);          // 4 MiB
  u16* PH = (u16*)(ws + 4194304);    // 4 MiB
  u16* G  = (u16*)(ws + 8388608);    // 4 MiB
  u16* U  = (u16*)(ws + 12582912);   // SPLIT * 4 MiB bf16 partials (or Y for SPLIT==1)
  const size_t NEED4 = 12582912 + 4u*4194304 + 524288;   // 29,884,416
  const size_t NEED2 = 12582912 + 2u*4194304 + 262144;   // 21,233,664
  int split = (ws_size >= NEED4) ? 4 : (ws_size >= NEED2) ? 2 : 1;
  float* ML = (float*)(ws + 12582912 + (size_t)split * 4194304);

  dim3 gp(64, BATCH, 2);
  k_proj_all<<<gp, 256, 0, stream>>>(q_in, ref, Wt, bt, Wp, bp, Wg, bg, TH, PH, G);

  dim3 go(64, 2, BATCH);
  if (split == 4) {
    k_attn<4><<<512, 256, 0, stream>>>(TH, PH, G, U, ML, U);
    k_outproj<4><<<go, 256, 0, stream>>>(q_in, Wo, bo, U, ML, out);
  } else if (split == 2) {
    k_attn<2><<<256, 256, 0, stream>>>(TH, PH, G, U, ML, U);
    k_outproj<2><<<go, 256, 0, stream>>>(q_in, Wo, bo, U, ML, out);
  } else {
    k_attn<1><<<128, 256, 0, stream>>>(TH, PH, G, U, ML, U);
    k_outproj<1><<<go, 256, 0, stream>>>(q_in, Wo, bo, U, ML, out);
  }
}